// Round 25
// baseline (1856.307 us; speedup 1.0000x reference)
//
#include <hip/hip_runtime.h>

#define SKIPF 0.70710678118654752440f

typedef unsigned short u16;
typedef unsigned int u32;
typedef __attribute__((ext_vector_type(4))) short bf16x4;
typedef __attribute__((ext_vector_type(8))) short bf16x8;
typedef __attribute__((ext_vector_type(4))) float f32x4;

#define MFMA32(A, B, C) __builtin_amdgcn_mfma_f32_16x16x32_bf16(A, B, C, 0, 0, 0)
#define MFMA16(A, B, C) __builtin_amdgcn_mfma_f32_16x16x16bf16_1k(A, B, C, 0, 0, 0)

__device__ __forceinline__ float bf2f(u16 v) {
  u32 u = ((u32)v) << 16; float f; __builtin_memcpy(&f, &u, 4); return f;
}
__device__ __forceinline__ u16 f2bf(float f) {
  u32 u; __builtin_memcpy(&u, &f, 4);
  u = (u + 0x7fffu + ((u >> 16) & 1u)) >> 16;
  return (u16)u;
}
// packed bf16 convert (RNE), lo = a, hi = b
__device__ __forceinline__ u32 cvtpk(float a, float b) {
  u32 r;
  asm("v_cvt_pk_bf16_f32 %0, %1, %2" : "=v"(r) : "v"(a), "v"(b));
  return r;
}
__device__ __forceinline__ void gload16(const void* g, void* s) {
  __builtin_amdgcn_global_load_lds((const __attribute__((address_space(1))) void*)g,
                                   (__attribute__((address_space(3))) void*)s, 16, 0, 0);
}

// ---------------- adaLN: silu fused, grid (24,32), unroll-4 ----------------
__global__ __launch_bounds__(256) void adaln_part_kernel(const float* __restrict__ c,
                                                         const float* __restrict__ t,
                                                         const float* __restrict__ aw,
                                                         float* __restrict__ part) {
  __shared__ float sc[4][32];
  int n = blockIdx.x * 256 + threadIdx.x;
  int ks = blockIdx.y;
  int k0 = ks * 32;
  if (threadIdx.x < 128) {
    int b = threadIdx.x >> 5, kk = threadIdx.x & 31;
    float xx = (c[b * 1024 + k0 + kk] + t[b * 1024 + k0 + kk]) * SKIPF;
    sc[b][kk] = xx / (1.f + __expf(-xx));
  }
  __syncthreads();
  float a0 = 0.f, a1 = 0.f, a2 = 0.f, a3 = 0.f;
#pragma unroll 4
  for (int k = 0; k < 32; ++k) {
    float w = aw[(size_t)(k0 + k) * 6144 + n];
    a0 += sc[0][k] * w; a1 += sc[1][k] * w; a2 += sc[2][k] * w; a3 += sc[3][k] * w;
  }
  part[(size_t)(ks * 4 + 0) * 6144 + n] = a0;
  part[(size_t)(ks * 4 + 1) * 6144 + n] = a1;
  part[(size_t)(ks * 4 + 2) * 6144 + n] = a2;
  part[(size_t)(ks * 4 + 3) * 6144 + n] = a3;
}

__global__ void adaln_reduce_kernel(const float* __restrict__ part, const float* __restrict__ ab,
                                    float* __restrict__ mod) {
  int i = blockIdx.x * 256 + threadIdx.x;  // 24576 = 4*6144
  int b = i / 6144, n = i - b * 6144;
  float a = ab[n];
#pragma unroll 4
  for (int ks = 0; ks < 32; ++ks) a += part[(size_t)(ks * 4 + b) * 6144 + n];
  mod[(size_t)b * 6144 + n] = a;
}

// batched W (K x N) f32 -> WT (N x K) bf16 for all 4 weights. block (32,8), grid 12288.
__global__ void wtrans4_kernel(const float* __restrict__ wq, u16* __restrict__ oq,
                               const float* __restrict__ wp, u16* __restrict__ op,
                               const float* __restrict__ w1p, u16* __restrict__ o1,
                               const float* __restrict__ w2p, u16* __restrict__ o2) {
  __shared__ float tile[32][33];
  int bid = blockIdx.x;
  const float* W; u16* WT; int nx, K, N, base;
  if (bid < 3072)      { W = wq;  WT = oq; nx = 96;  K = 1024; N = 3072; base = 0; }
  else if (bid < 4096) { W = wp;  WT = op; nx = 32;  K = 1024; N = 1024; base = 3072; }
  else if (bid < 8192) { W = w1p; WT = o1; nx = 128; K = 1024; N = 4096; base = 4096; }
  else                 { W = w2p; WT = o2; nx = 32;  K = 4096; N = 1024; base = 8192; }
  int t = bid - base;
  int n0 = (t % nx) * 32, k0 = (t / nx) * 32;
  int tx = threadIdx.x, ty = threadIdx.y;
#pragma unroll
  for (int i = 0; i < 4; ++i)
    tile[ty * 4 + i][tx] = W[(size_t)(k0 + ty * 4 + i) * N + n0 + tx];
  __syncthreads();
#pragma unroll
  for (int i = 0; i < 4; ++i)
    WT[(size_t)(n0 + ty * 4 + i) * K + k0 + tx] = f2bf(tile[tx][ty * 4 + i]);
}

// LN + adaLN modulate; reads xin (f32), writes bf16 h
__global__ __launch_bounds__(256) void ln_mod_kernel(const float* __restrict__ xin,
                                                     const float* __restrict__ mod,
                                                     u16* __restrict__ h, int sh_off, int sc_off) {
  int row = blockIdx.x;
  int b = row >> 10;
  const float4* xr = (const float4*)(xin + (size_t)row * 1024);
  float4 v = xr[threadIdx.x];
  float s = v.x + v.y + v.z + v.w;
  float ss = v.x * v.x + v.y * v.y + v.z * v.z + v.w * v.w;
#pragma unroll
  for (int o = 32; o; o >>= 1) { s += __shfl_xor(s, o); ss += __shfl_xor(ss, o); }
  __shared__ float red[8];
  int wave = threadIdx.x >> 6;
  if ((threadIdx.x & 63) == 0) { red[wave * 2] = s; red[wave * 2 + 1] = ss; }
  __syncthreads();
  s = red[0] + red[2] + red[4] + red[6];
  ss = red[1] + red[3] + red[5] + red[7];
  float mu = s * (1.f / 1024.f);
  float var = ss * (1.f / 1024.f) - mu * mu;
  float rs = rsqrtf(var + 1e-6f);
  int n = threadIdx.x * 4;
  const float* mb = mod + (size_t)b * 6144;
  float4 sc = *(const float4*)(mb + sc_off + n);
  float4 sh = *(const float4*)(mb + sh_off + n);
  ushort4 o4;
  o4.x = f2bf(((v.x - mu) * rs * (1.f + sc.x) + sh.x) * SKIPF);
  o4.y = f2bf(((v.y - mu) * rs * (1.f + sc.y) + sh.y) * SKIPF);
  o4.z = f2bf(((v.z - mu) * rs * (1.f + sc.z) + sh.z) * SKIPF);
  o4.w = f2bf(((v.w - mu) * rs * (1.f + sc.w) + sh.w) * SKIPF);
  *(ushort4*)(h + (size_t)row * 1024 + n) = o4;
}

// ---------------- GEMM 256x256, BK=32, 8 waves, 4-slot ring, counted vmcnt(8), ----------------
// staging loads spread between MFMA clusters (no intra-tile barriers).
// EPI 0: bf16 store. EPI 1: gelu -> bf16. EPI 2: fused RoPE+scatter (qkv).
template <int EPI>
__global__ __launch_bounds__(512, 1) void gemm256r_kernel(
    const u16* __restrict__ A, const u16* __restrict__ BT, const float* __restrict__ bias,
    u16* __restrict__ Cb, int NBX, int N, int K,
    const float* __restrict__ cosb, const float* __restrict__ sinb,
    u16* __restrict__ qo, u16* __restrict__ ko, u16* __restrict__ vto) {
  __shared__ u16 lds[4][16384];  // slot: A [128][64] (16KB) then B [128][64] (16KB)
  const int tid = threadIdx.x;
  const int lane = tid & 63, wave = tid >> 6;
  const int lq = lane & 15, lk = lane >> 4;
  const int wr = wave >> 2, wc = wave & 3;  // wave tile 128 x 64

  int per = gridDim.x >> 3;
  int swz = (blockIdx.x & 7) * per + (blockIdx.x >> 3);  // XCD chunk swizzle (grid%8==0)
  int bx = swz % NBX, by = swz / NBX;
  const int m0 = by * 256, n0 = bx * 256;

  f32x4 acc[8][4];
#pragma unroll
  for (int i = 0; i < 8; ++i)
#pragma unroll
    for (int j = 0; j < 4; ++j) acc[i][j] = (f32x4){0.f, 0.f, 0.f, 0.f};

  // one of the 4 per-thread staging loads for tile t into `slot`
  auto STAGE_ONE = [&](int slot, int t, int part) {
    int kt = t * 32;
    int u = tid + (part & 1) * 512;
    int r = u >> 3, cpos = u & 7;
    int g = cpos ^ (r & 7);  // pre-swizzled source chunk
    if (part < 2) {
      gload16(A + (size_t)(m0 + 2 * r + (g >> 2)) * K + kt + (g & 3) * 8,
              (char*)lds[slot] + u * 16);
    } else {
      gload16(BT + (size_t)(n0 + 2 * r + (g >> 2)) * K + kt + (g & 3) * 8,
              (char*)(lds[slot] + 8192) + u * 16);
    }
  };
  auto STAGE = [&](int slot, int t) {
#pragma unroll
    for (int p = 0; p < 4; ++p) STAGE_ONE(slot, t, p);
  };

  const int NT = K >> 5;
  STAGE(0, 0); STAGE(1, 1); STAGE(2, 2);
  int slot = 0;
  for (int t = 0; t < NT; ++t) {
    int rem = NT - 1 - t;
    if (rem >= 2) asm volatile("s_waitcnt vmcnt(8)" ::: "memory");
    else if (rem == 1) asm volatile("s_waitcnt vmcnt(4)" ::: "memory");
    else asm volatile("s_waitcnt vmcnt(0)" ::: "memory");
    __builtin_amdgcn_s_barrier();
    __builtin_amdgcn_sched_barrier(0);
    const char* Ab = (const char*)lds[slot];
    const char* Bb = (const char*)(lds[slot] + 8192);
    int ns = slot + 3; if (ns >= 4) ns -= 4;
    bool pre = (t + 3 < NT);
    bf16x8 bfr[4];
#pragma unroll
    for (int ni = 0; ni < 4; ++ni) {
      int nrow = wc * 64 + ni * 16 + lq;
      int r = nrow >> 1, g = (nrow & 1) * 4 + lk;
      bfr[ni] = *(const bf16x8*)(Bb + r * 128 + ((g ^ (r & 7)) << 4));
    }
#pragma unroll
    for (int ph = 0; ph < 4; ++ph) {
      if (pre) STAGE_ONE(ns, t + 3, ph);
      bf16x8 af0, af1;
      {
        int mrow = wr * 128 + (ph * 2) * 16 + lq;
        int r = mrow >> 1, g = (mrow & 1) * 4 + lk;
        af0 = *(const bf16x8*)(Ab + r * 128 + ((g ^ (r & 7)) << 4));
        mrow += 16;
        r = mrow >> 1; g = (mrow & 1) * 4 + lk;
        af1 = *(const bf16x8*)(Ab + r * 128 + ((g ^ (r & 7)) << 4));
      }
      __builtin_amdgcn_s_setprio(1);
#pragma unroll
      for (int j = 0; j < 4; ++j) acc[ph * 2][j] = MFMA32(af0, bfr[j], acc[ph * 2][j]);
#pragma unroll
      for (int j = 0; j < 4; ++j) acc[ph * 2 + 1][j] = MFMA32(af1, bfr[j], acc[ph * 2 + 1][j]);
      __builtin_amdgcn_s_setprio(0);
    }
    ++slot; if (slot >= 4) slot = 0;
  }

#pragma unroll
  for (int i = 0; i < 8; ++i) {
    int rbase = m0 + wr * 128 + i * 16 + lk * 4;
#pragma unroll
    for (int j = 0; j < 4; ++j) {
      int cg = n0 + wc * 64 + j * 16 + lq;
      float bv = bias[cg];
      if (EPI == 2) {
        int region = cg >> 10;       // block-uniform: 0=q, 1=k, 2=v
        int cgr = cg & 1023;
        int hh = cgr >> 6, d = cgr & 63;
        int b = rbase >> 10, l0 = rbase & 1023;
        if (region < 2) {
#pragma unroll
          for (int r = 0; r < 4; ++r) {
            int l = l0 + r;
            float val = acc[i][j][r] + bv;
            float partner = __shfl_xor(val, 1);
            float cc = cosb[l * 64 + d], sn = sinb[l * 64 + d];
            float out = (d & 1) ? (val * cc + partner * sn) : (val * cc - partner * sn);
            if (region == 0) out *= 0.125f;
            u16* dst = (region == 0) ? qo : ko;
            dst[((size_t)(b * 16 + hh) * 1024 + l) * 64 + d] = f2bf(out);
          }
        } else {
          union { ushort4 s4; u32 w[2]; } vv;
          vv.w[0] = cvtpk(acc[i][j][0] + bv, acc[i][j][1] + bv);
          vv.w[1] = cvtpk(acc[i][j][2] + bv, acc[i][j][3] + bv);
          *(ushort4*)(vto + (size_t)(b * 16 + hh) * 65536 + (size_t)d * 1024 + l0) = vv.s4;
        }
      } else {
#pragma unroll
        for (int r = 0; r < 4; ++r) {
          int row = rbase + r;
          float val = acc[i][j][r] + bv;
          if (EPI == 0) {
            Cb[(size_t)row * N + cg] = f2bf(val);
          } else {
            float tt = 0.7978845608028654f * (val + 0.044715f * val * val * val);
            float e = __expf(2.f * tt);
            float th = 1.f - 2.f / (e + 1.f);
            Cb[(size_t)row * N + cg] = f2bf(0.5f * val * (1.f + th));
          }
        }
      }
    }
  }
}

// ---------------- GEMM 128x128, BK=32, 4 waves, 3-slot ring, residual epilogue ----------------
__global__ __launch_bounds__(256) void gemm_res128_kernel(
    const u16* __restrict__ A, const u16* __restrict__ BT, const float* __restrict__ bias,
    const float* __restrict__ xin, float* __restrict__ xout, const float* __restrict__ mod,
    int g_off, int K) {
  __shared__ u16 lds[3][8192];  // slot: A [64 rows][128B] 4KB, then B 4KB
  const int tid = threadIdx.x;
  const int lane = tid & 63, wave = tid >> 6;
  const int lq = lane & 15, lk = lane >> 4;
  const int wr = wave >> 1, wc = wave & 1;  // wave tile 64 x 64
  const int m0 = blockIdx.x * 128, n0 = blockIdx.y * 128;

  f32x4 acc[4][4];
#pragma unroll
  for (int i = 0; i < 4; ++i)
#pragma unroll
    for (int j = 0; j < 4; ++j) acc[i][j] = (f32x4){0.f, 0.f, 0.f, 0.f};

  auto STAGE = [&](int slot, int t) {
    int kt = t * 32;
    char* Ab = (char*)lds[slot];
    char* Bb = (char*)(lds[slot] + 4096);
#pragma unroll
    for (int q = 0; q < 2; ++q) {
      int u = tid + q * 256;         // 512 chunks each for A and B
      int r = u >> 3, cpos = u & 7;
      int g = cpos ^ (r & 7);        // pre-swizzled source chunk
      gload16(A + (size_t)(m0 + 2 * r + (g >> 2)) * K + kt + (g & 3) * 8, Ab + u * 16);
      gload16(BT + (size_t)(n0 + 2 * r + (g >> 2)) * K + kt + (g & 3) * 8, Bb + u * 16);
    }
  };

  const int NT = K >> 5;
  STAGE(0, 0); STAGE(1, 1);
  int slot = 0;
  for (int t = 0; t < NT; ++t) {
    if (t + 1 < NT) asm volatile("s_waitcnt vmcnt(4)" ::: "memory");
    else asm volatile("s_waitcnt vmcnt(0)" ::: "memory");
    __builtin_amdgcn_s_barrier();
    __builtin_amdgcn_sched_barrier(0);
    if (t + 2 < NT) { int ns = slot + 2; if (ns >= 3) ns -= 3; STAGE(ns, t + 2); }
    const char* Ab = (const char*)lds[slot];
    const char* Bb = (const char*)(lds[slot] + 4096);
    bf16x8 af[4], bfr[4];
#pragma unroll
    for (int i = 0; i < 4; ++i) {
      int mrow = wr * 64 + i * 16 + lq;
      int r = mrow >> 1, g = (mrow & 1) * 4 + lk;
      af[i] = *(const bf16x8*)(Ab + r * 128 + ((g ^ (r & 7)) << 4));
    }
#pragma unroll
    for (int j = 0; j < 4; ++j) {
      int nrow = wc * 64 + j * 16 + lq;
      int r = nrow >> 1, g = (nrow & 1) * 4 + lk;
      bfr[j] = *(const bf16x8*)(Bb + r * 128 + ((g ^ (r & 7)) << 4));
    }
    __builtin_amdgcn_s_setprio(1);
#pragma unroll
    for (int i = 0; i < 4; ++i)
#pragma unroll
      for (int j = 0; j < 4; ++j) acc[i][j] = MFMA32(af[i], bfr[j], acc[i][j]);
    __builtin_amdgcn_s_setprio(0);
    ++slot; if (slot >= 3) slot = 0;
  }

#pragma unroll
  for (int i = 0; i < 4; ++i) {
    int rbase = m0 + wr * 64 + i * 16 + lk * 4;
#pragma unroll
    for (int j = 0; j < 4; ++j) {
      int cg = n0 + wc * 64 + j * 16 + lq;
      float bv = bias[cg];
#pragma unroll
      for (int r = 0; r < 4; ++r) {
        int row = rbase + r;
        float val = acc[i][j][r] + bv;
        int b = row >> 10;
        float g = mod[(size_t)b * 6144 + g_off + cg];
        float xv = xin[(size_t)row * 1024 + cg];
        xout[(size_t)row * 1024 + cg] = (xv + g * val) * SKIPF;
      }
    }
  }
}

// ---------------- flash attention: 1024 blocks (16 qt x 64 bh), 16 q-rows/wave, ----------------
// 3-slot LDS ring (48 KB -> 3 blocks/CU), counted vmcnt(4): loads stay in flight across barriers.
__global__ __launch_bounds__(256) void attn_kernel(const u16* __restrict__ qb,
                                                   const u16* __restrict__ kb,
                                                   const u16* __restrict__ vt,
                                                   u16* __restrict__ ob) {
  __shared__ u16 ktile[3][4096];
  __shared__ u16 vtile[3][4096];
  int nid = (blockIdx.x & 7) * 128 + (blockIdx.x >> 3);  // XCD chunk swizzle: 8 bh per XCD
  int qt = nid & 15, bh = nid >> 4;
  int tid = threadIdx.x;
  int lane = tid & 63, wave = tid >> 6;
  int lq = lane & 15, lk = lane >> 4;
  const u16* Q = qb + (size_t)bh * 65536;
  const u16* Kp = kb + (size_t)bh * 65536;
  const u16* VT = vt + (size_t)bh * 65536;
  int qbase = qt * 64 + wave * 16;

  bf16x8 qf0 = *(const bf16x8*)(Q + (size_t)(qbase + lq) * 64 + lk * 8);
  bf16x8 qf1 = *(const bf16x8*)(Q + (size_t)(qbase + lq) * 64 + 32 + lk * 8);

  auto stage_one = [&](int buf, int kvb, int u) {
    int r = u >> 3;
    int cc = ((u & 7) ^ (r & 7)) * 8;
    gload16(Kp + (size_t)(kvb + r) * 64 + cc, (char*)ktile[buf] + u * 16);
    gload16(VT + (size_t)r * 1024 + kvb + cc, (char*)vtile[buf] + u * 16);
  };

  float mrun = -1e30f, lsum = 0.f;
  f32x4 oacc[4];
#pragma unroll
  for (int f = 0; f < 4; ++f) oacc[f] = (f32x4){0.f, 0.f, 0.f, 0.f};
  const f32x4 z4 = (f32x4){0.f, 0.f, 0.f, 0.f};

  stage_one(0, 0, tid); stage_one(0, 0, tid + 256);
  stage_one(1, 64, tid); stage_one(1, 64, tid + 256);
  int slot = 0;
  for (int t = 0; t < 16; ++t) {
    if (t + 1 < 16) asm volatile("s_waitcnt vmcnt(4)" ::: "memory");
    else asm volatile("s_waitcnt vmcnt(0)" ::: "memory");
    __builtin_amdgcn_s_barrier();
    __builtin_amdgcn_sched_barrier(0);
    if (t + 2 < 16) {
      int ns = slot + 2; if (ns >= 3) ns -= 3;
      stage_one(ns, (t + 2) * 64, tid);
      stage_one(ns, (t + 2) * 64, tid + 256);
    }
    const char* kb_ = (const char*)ktile[slot];
    const char* vb_ = (const char*)vtile[slot];
    f32x4 st[4];
    __builtin_amdgcn_s_setprio(1);
#pragma unroll
    for (int s = 0; s < 4; ++s) {
      int r = s * 16 + lq;
      int sw = (r & 7) << 4;
      bf16x8 kf0 = *(const bf16x8*)(kb_ + r * 128 + ((lk * 16) ^ sw));
      bf16x8 kf1 = *(const bf16x8*)(kb_ + r * 128 + ((64 + lk * 16) ^ sw));
      st[s] = MFMA32(kf0, qf0, z4);
      st[s] = MFMA32(kf1, qf1, st[s]);
    }
    __builtin_amdgcn_s_setprio(0);
    float pm = -1e30f;
#pragma unroll
    for (int s = 0; s < 4; ++s)
#pragma unroll
      for (int r = 0; r < 4; ++r) pm = fmaxf(pm, st[s][r]);
    pm = fmaxf(pm, __shfl_xor(pm, 16));
    pm = fmaxf(pm, __shfl_xor(pm, 32));
    if (!__all(pm - mrun <= 8.f)) {
      float mnew = fmaxf(mrun, pm);
      float corr = __expf(mrun - mnew);
      float c0 = __shfl(corr, lk * 4 + 0), c1 = __shfl(corr, lk * 4 + 1);
      float c2 = __shfl(corr, lk * 4 + 2), c3 = __shfl(corr, lk * 4 + 3);
#pragma unroll
      for (int f = 0; f < 4; ++f) {
        oacc[f][0] *= c0; oacc[f][1] *= c1;
        oacc[f][2] *= c2; oacc[f][3] *= c3;
      }
      lsum *= corr;
      mrun = mnew;
    }
    bf16x4 pf[4];
    float ps = 0.f;
#pragma unroll
    for (int s = 0; s < 4; ++s) {
      float p0 = __expf(st[s][0] - mrun);
      float p1 = __expf(st[s][1] - mrun);
      float p2 = __expf(st[s][2] - mrun);
      float p3 = __expf(st[s][3] - mrun);
      ps += p0 + p1 + p2 + p3;
      union { bf16x4 v; u32 w[2]; } pu;
      pu.w[0] = cvtpk(p0, p1);
      pu.w[1] = cvtpk(p2, p3);
      pf[s] = pu.v;
    }
    ps += __shfl_xor(ps, 16);
    ps += __shfl_xor(ps, 32);
    lsum += ps;
    __builtin_amdgcn_s_setprio(1);
#pragma unroll
    for (int f = 0; f < 4; ++f) {
      int r = lq + f * 16;
      int sw = (r & 7) << 4;
#pragma unroll
      for (int s = 0; s < 4; ++s) {
        bf16x4 vf = *(const bf16x4*)(vb_ + r * 128 + ((s * 32 + lk * 8) ^ sw));
        oacc[f] = MFMA16(pf[s], vf, oacc[f]);
      }
    }
    __builtin_amdgcn_s_setprio(0);
    ++slot; if (slot >= 3) slot = 0;
  }

  int b = bh >> 4, hh = bh & 15;
  float inv = 1.f / lsum;
  float i0 = __shfl(inv, lk * 4 + 0), i1 = __shfl(inv, lk * 4 + 1);
  float i2 = __shfl(inv, lk * 4 + 2), i3 = __shfl(inv, lk * 4 + 3);
#pragma unroll
  for (int f = 0; f < 4; ++f) {
#pragma unroll
    for (int j = 0; j < 4; ++j) {
      int qrow = qbase + lk * 4 + j;
      float sc = (j == 0) ? i0 : (j == 1) ? i1 : (j == 2) ? i2 : i3;
      ob[((size_t)(b * 1024 + qrow)) * 1024 + hh * 64 + lq + f * 16] = f2bf(oacc[f][j] * sc);
    }
  }
}

// ---------------- launch ----------------

extern "C" void kernel_launch(void* const* d_in, const int* in_sizes, int n_in,
                              void* d_out, int out_size, void* d_ws, size_t ws_size,
                              hipStream_t stream) {
  const float* x = (const float*)d_in[0];
  const float* c = (const float*)d_in[1];
  const float* t = (const float*)d_in[2];
  const float* cosb = (const float*)d_in[4];
  const float* sinb = (const float*)d_in[5];
  const float* qkv_w = (const float*)d_in[6];
  const float* qkv_b = (const float*)d_in[7];
  const float* proj_w = (const float*)d_in[8];
  const float* proj_b = (const float*)d_in[9];
  const float* w1 = (const float*)d_in[10];
  const float* b1 = (const float*)d_in[11];
  const float* w2 = (const float*)d_in[12];
  const float* b2 = (const float*)d_in[13];
  const float* aw = (const float*)d_in[14];
  const float* ab = (const float*)d_in[15];

  constexpr size_t OFF_X = 0;                          // 16 MB f32 residual
  constexpr size_t OFF_H = OFF_X + 16777216;           // 8 MB bf16 h
  constexpr size_t OFF_BIG = OFF_H + 8388608;          // 32 MB bf16 m1
  constexpr size_t OFF_Q = OFF_BIG + 33554432;         // 8 MB
  constexpr size_t OFF_K = OFF_Q + 8388608;
  constexpr size_t OFF_V = OFF_K + 8388608;            // vt [bh][d][l]
  constexpr size_t OFF_AO = OFF_V + 8388608;
  constexpr size_t OFF_WQ = OFF_AO + 8388608;          // 6 MB bf16 qkv_w^T
  constexpr size_t OFF_WP = OFF_WQ + 6291456;          // 2 MB
  constexpr size_t OFF_W1 = OFF_WP + 2097152;          // 8 MB
  constexpr size_t OFF_W2 = OFF_W1 + 8388608;          // 8 MB
  constexpr size_t OFF_MOD = OFF_W2 + 8388608;         // mod 96 KB
  constexpr size_t OFF_PART = OFF_MOD + 98304;         // partials 3 MB

  char* ws = (char*)d_ws;
  float* x_cur = (float*)(ws + OFF_X);
  u16* h = (u16*)(ws + OFF_H);
  u16* big = (u16*)(ws + OFF_BIG);
  u16* qv = (u16*)(ws + OFF_Q);
  u16* kv = (u16*)(ws + OFF_K);
  u16* vt = (u16*)(ws + OFF_V);
  u16* ao = (u16*)(ws + OFF_AO);
  u16* wTq = (u16*)(ws + OFF_WQ);
  u16* wTp = (u16*)(ws + OFF_WP);
  u16* wT1 = (u16*)(ws + OFF_W1);
  u16* wT2 = (u16*)(ws + OFF_W2);
  float* mod = (float*)(ws + OFF_MOD);
  float* part = (float*)(ws + OFF_PART);

  for (int L = 0; L < 8; ++L) {
    const float* awL = aw + (size_t)L * 1024 * 6144;
    const float* abL = ab + (size_t)L * 6144;
    const float* qwL = qkv_w + (size_t)L * 1024 * 3072;
    const float* qbL = qkv_b + (size_t)L * 3072;
    const float* pwL = proj_w + (size_t)L * 1024 * 1024;
    const float* pbL = proj_b + (size_t)L * 1024;
    const float* w1L = w1 + (size_t)L * 1024 * 4096;
    const float* b1L = b1 + (size_t)L * 4096;
    const float* w2L = w2 + (size_t)L * 4096 * 1024;
    const float* b2L = b2 + (size_t)L * 1024;

    const float* xin = (L == 0) ? x : x_cur;
    float* xout2 = (L == 7) ? (float*)d_out : x_cur;

    adaln_part_kernel<<<dim3(24, 32), 256, 0, stream>>>(c, t, awL, part);
    adaln_reduce_kernel<<<96, 256, 0, stream>>>(part, abL, mod);
    wtrans4_kernel<<<12288, dim3(32, 8), 0, stream>>>(qwL, wTq, pwL, wTp, w1L, wT1, w2L, wT2);

    ln_mod_kernel<<<4096, 256, 0, stream>>>(xin, mod, h, 0, 1024);
    gemm256r_kernel<2><<<192, 512, 0, stream>>>(h, wTq, qbL, nullptr, 12, 3072, 1024,
                                                cosb, sinb, qv, kv, vt);
    attn_kernel<<<1024, 256, 0, stream>>>(qv, kv, vt, ao);
    gemm_res128_kernel<<<dim3(32, 8), 256, 0, stream>>>(ao, wTp, pbL, xin, x_cur, mod, 2048, 1024);
    ln_mod_kernel<<<4096, 256, 0, stream>>>(x_cur, mod, h, 3072, 4096);
    gemm256r_kernel<1><<<256, 512, 0, stream>>>(h, wT1, b1L, big, 16, 4096, 1024,
                                                nullptr, nullptr, nullptr, nullptr, nullptr);
    gemm_res128_kernel<<<dim3(32, 8), 256, 0, stream>>>(big, wT2, b2L, x_cur, xout2, mod, 5120, 4096);
  }
}

// Round 26
// 1774.710 us; speedup vs baseline: 1.0460x; 1.0460x over previous
//
#include <hip/hip_runtime.h>

#define SKIPF 0.70710678118654752440f

typedef unsigned short u16;
typedef unsigned int u32;
typedef __attribute__((ext_vector_type(4))) short bf16x4;
typedef __attribute__((ext_vector_type(8))) short bf16x8;
typedef __attribute__((ext_vector_type(4))) float f32x4;

#define MFMA32(A, B, C) __builtin_amdgcn_mfma_f32_16x16x32_bf16(A, B, C, 0, 0, 0)
#define MFMA16(A, B, C) __builtin_amdgcn_mfma_f32_16x16x16bf16_1k(A, B, C, 0, 0, 0)

__device__ __forceinline__ float bf2f(u16 v) {
  u32 u = ((u32)v) << 16; float f; __builtin_memcpy(&f, &u, 4); return f;
}
__device__ __forceinline__ u16 f2bf(float f) {
  u32 u; __builtin_memcpy(&u, &f, 4);
  u = (u + 0x7fffu + ((u >> 16) & 1u)) >> 16;
  return (u16)u;
}
// packed bf16 convert (RNE), lo = a, hi = b
__device__ __forceinline__ u32 cvtpk(float a, float b) {
  u32 r;
  asm("v_cvt_pk_bf16_f32 %0, %1, %2" : "=v"(r) : "v"(a), "v"(b));
  return r;
}
__device__ __forceinline__ void gload16(const void* g, void* s) {
  __builtin_amdgcn_global_load_lds((const __attribute__((address_space(1))) void*)g,
                                   (__attribute__((address_space(3))) void*)s, 16, 0, 0);
}

// ---------------- adaLN: silu fused, grid (24,32), unroll-4 ----------------
__global__ __launch_bounds__(256) void adaln_part_kernel(const float* __restrict__ c,
                                                         const float* __restrict__ t,
                                                         const float* __restrict__ aw,
                                                         float* __restrict__ part) {
  __shared__ float sc[4][32];
  int n = blockIdx.x * 256 + threadIdx.x;
  int ks = blockIdx.y;
  int k0 = ks * 32;
  if (threadIdx.x < 128) {
    int b = threadIdx.x >> 5, kk = threadIdx.x & 31;
    float xx = (c[b * 1024 + k0 + kk] + t[b * 1024 + k0 + kk]) * SKIPF;
    sc[b][kk] = xx / (1.f + __expf(-xx));
  }
  __syncthreads();
  float a0 = 0.f, a1 = 0.f, a2 = 0.f, a3 = 0.f;
#pragma unroll 4
  for (int k = 0; k < 32; ++k) {
    float w = aw[(size_t)(k0 + k) * 6144 + n];
    a0 += sc[0][k] * w; a1 += sc[1][k] * w; a2 += sc[2][k] * w; a3 += sc[3][k] * w;
  }
  part[(size_t)(ks * 4 + 0) * 6144 + n] = a0;
  part[(size_t)(ks * 4 + 1) * 6144 + n] = a1;
  part[(size_t)(ks * 4 + 2) * 6144 + n] = a2;
  part[(size_t)(ks * 4 + 3) * 6144 + n] = a3;
}

__global__ void adaln_reduce_kernel(const float* __restrict__ part, const float* __restrict__ ab,
                                    float* __restrict__ mod) {
  int i = blockIdx.x * 256 + threadIdx.x;  // 24576 = 4*6144
  int b = i / 6144, n = i - b * 6144;
  float a = ab[n];
#pragma unroll 4
  for (int ks = 0; ks < 32; ++ks) a += part[(size_t)(ks * 4 + b) * 6144 + n];
  mod[(size_t)b * 6144 + n] = a;
}

// batched W (K x N) f32 -> WT (N x K) bf16 for all 4 weights. block (32,8), grid 12288.
__global__ void wtrans4_kernel(const float* __restrict__ wq, u16* __restrict__ oq,
                               const float* __restrict__ wp, u16* __restrict__ op,
                               const float* __restrict__ w1p, u16* __restrict__ o1,
                               const float* __restrict__ w2p, u16* __restrict__ o2) {
  __shared__ float tile[32][33];
  int bid = blockIdx.x;
  const float* W; u16* WT; int nx, K, N, base;
  if (bid < 3072)      { W = wq;  WT = oq; nx = 96;  K = 1024; N = 3072; base = 0; }
  else if (bid < 4096) { W = wp;  WT = op; nx = 32;  K = 1024; N = 1024; base = 3072; }
  else if (bid < 8192) { W = w1p; WT = o1; nx = 128; K = 1024; N = 4096; base = 4096; }
  else                 { W = w2p; WT = o2; nx = 32;  K = 4096; N = 1024; base = 8192; }
  int t = bid - base;
  int n0 = (t % nx) * 32, k0 = (t / nx) * 32;
  int tx = threadIdx.x, ty = threadIdx.y;
#pragma unroll
  for (int i = 0; i < 4; ++i)
    tile[ty * 4 + i][tx] = W[(size_t)(k0 + ty * 4 + i) * N + n0 + tx];
  __syncthreads();
#pragma unroll
  for (int i = 0; i < 4; ++i)
    WT[(size_t)(n0 + ty * 4 + i) * K + k0 + tx] = f2bf(tile[tx][ty * 4 + i]);
}

// LN + adaLN modulate; reads xin (f32), writes bf16 h
__global__ __launch_bounds__(256) void ln_mod_kernel(const float* __restrict__ xin,
                                                     const float* __restrict__ mod,
                                                     u16* __restrict__ h, int sh_off, int sc_off) {
  int row = blockIdx.x;
  int b = row >> 10;
  const float4* xr = (const float4*)(xin + (size_t)row * 1024);
  float4 v = xr[threadIdx.x];
  float s = v.x + v.y + v.z + v.w;
  float ss = v.x * v.x + v.y * v.y + v.z * v.z + v.w * v.w;
#pragma unroll
  for (int o = 32; o; o >>= 1) { s += __shfl_xor(s, o); ss += __shfl_xor(ss, o); }
  __shared__ float red[8];
  int wave = threadIdx.x >> 6;
  if ((threadIdx.x & 63) == 0) { red[wave * 2] = s; red[wave * 2 + 1] = ss; }
  __syncthreads();
  s = red[0] + red[2] + red[4] + red[6];
  ss = red[1] + red[3] + red[5] + red[7];
  float mu = s * (1.f / 1024.f);
  float var = ss * (1.f / 1024.f) - mu * mu;
  float rs = rsqrtf(var + 1e-6f);
  int n = threadIdx.x * 4;
  const float* mb = mod + (size_t)b * 6144;
  float4 sc = *(const float4*)(mb + sc_off + n);
  float4 sh = *(const float4*)(mb + sh_off + n);
  ushort4 o4;
  o4.x = f2bf(((v.x - mu) * rs * (1.f + sc.x) + sh.x) * SKIPF);
  o4.y = f2bf(((v.y - mu) * rs * (1.f + sc.y) + sh.y) * SKIPF);
  o4.z = f2bf(((v.z - mu) * rs * (1.f + sc.z) + sh.z) * SKIPF);
  o4.w = f2bf(((v.w - mu) * rs * (1.f + sc.w) + sh.w) * SKIPF);
  *(ushort4*)(h + (size_t)row * 1024 + n) = o4;
}

// ---------------- GEMM 256x256, BK=32, 8 waves, 4-slot ring, counted vmcnt(8), ----------------
// staging loads spread between MFMA clusters (no intra-tile barriers).
// EPI 0: bf16 store. EPI 1: gelu -> bf16. EPI 2: fused RoPE+scatter (qkv).
template <int EPI>
__global__ __launch_bounds__(512, 1) void gemm256r_kernel(
    const u16* __restrict__ A, const u16* __restrict__ BT, const float* __restrict__ bias,
    u16* __restrict__ Cb, int NBX, int N, int K,
    const float* __restrict__ cosb, const float* __restrict__ sinb,
    u16* __restrict__ qo, u16* __restrict__ ko, u16* __restrict__ vto) {
  __shared__ u16 lds[4][16384];  // slot: A [128][64] (16KB) then B [128][64] (16KB)
  const int tid = threadIdx.x;
  const int lane = tid & 63, wave = tid >> 6;
  const int lq = lane & 15, lk = lane >> 4;
  const int wr = wave >> 2, wc = wave & 3;  // wave tile 128 x 64

  int per = gridDim.x >> 3;
  int swz = (blockIdx.x & 7) * per + (blockIdx.x >> 3);  // XCD chunk swizzle (grid%8==0)
  int bx = swz % NBX, by = swz / NBX;
  const int m0 = by * 256, n0 = bx * 256;

  f32x4 acc[8][4];
#pragma unroll
  for (int i = 0; i < 8; ++i)
#pragma unroll
    for (int j = 0; j < 4; ++j) acc[i][j] = (f32x4){0.f, 0.f, 0.f, 0.f};

  // one of the 4 per-thread staging loads for tile t into `slot`
  auto STAGE_ONE = [&](int slot, int t, int part) {
    int kt = t * 32;
    int u = tid + (part & 1) * 512;
    int r = u >> 3, cpos = u & 7;
    int g = cpos ^ (r & 7);  // pre-swizzled source chunk
    if (part < 2) {
      gload16(A + (size_t)(m0 + 2 * r + (g >> 2)) * K + kt + (g & 3) * 8,
              (char*)lds[slot] + u * 16);
    } else {
      gload16(BT + (size_t)(n0 + 2 * r + (g >> 2)) * K + kt + (g & 3) * 8,
              (char*)(lds[slot] + 8192) + u * 16);
    }
  };
  auto STAGE = [&](int slot, int t) {
#pragma unroll
    for (int p = 0; p < 4; ++p) STAGE_ONE(slot, t, p);
  };

  const int NT = K >> 5;
  STAGE(0, 0); STAGE(1, 1); STAGE(2, 2);
  int slot = 0;
  for (int t = 0; t < NT; ++t) {
    int rem = NT - 1 - t;
    if (rem >= 2) asm volatile("s_waitcnt vmcnt(8)" ::: "memory");
    else if (rem == 1) asm volatile("s_waitcnt vmcnt(4)" ::: "memory");
    else asm volatile("s_waitcnt vmcnt(0)" ::: "memory");
    __builtin_amdgcn_s_barrier();
    __builtin_amdgcn_sched_barrier(0);
    const char* Ab = (const char*)lds[slot];
    const char* Bb = (const char*)(lds[slot] + 8192);
    int ns = slot + 3; if (ns >= 4) ns -= 4;
    bool pre = (t + 3 < NT);
    bf16x8 bfr[4];
#pragma unroll
    for (int ni = 0; ni < 4; ++ni) {
      int nrow = wc * 64 + ni * 16 + lq;
      int r = nrow >> 1, g = (nrow & 1) * 4 + lk;
      bfr[ni] = *(const bf16x8*)(Bb + r * 128 + ((g ^ (r & 7)) << 4));
    }
#pragma unroll
    for (int ph = 0; ph < 4; ++ph) {
      if (pre) STAGE_ONE(ns, t + 3, ph);
      bf16x8 af0, af1;
      {
        int mrow = wr * 128 + (ph * 2) * 16 + lq;
        int r = mrow >> 1, g = (mrow & 1) * 4 + lk;
        af0 = *(const bf16x8*)(Ab + r * 128 + ((g ^ (r & 7)) << 4));
        mrow += 16;
        r = mrow >> 1; g = (mrow & 1) * 4 + lk;
        af1 = *(const bf16x8*)(Ab + r * 128 + ((g ^ (r & 7)) << 4));
      }
      __builtin_amdgcn_s_setprio(1);
#pragma unroll
      for (int j = 0; j < 4; ++j) acc[ph * 2][j] = MFMA32(af0, bfr[j], acc[ph * 2][j]);
#pragma unroll
      for (int j = 0; j < 4; ++j) acc[ph * 2 + 1][j] = MFMA32(af1, bfr[j], acc[ph * 2 + 1][j]);
      __builtin_amdgcn_s_setprio(0);
    }
    ++slot; if (slot >= 4) slot = 0;
  }

#pragma unroll
  for (int i = 0; i < 8; ++i) {
    int rbase = m0 + wr * 128 + i * 16 + lk * 4;
#pragma unroll
    for (int j = 0; j < 4; ++j) {
      int cg = n0 + wc * 64 + j * 16 + lq;
      float bv = bias[cg];
      if (EPI == 2) {
        int region = cg >> 10;       // block-uniform: 0=q, 1=k, 2=v
        int cgr = cg & 1023;
        int hh = cgr >> 6, d = cgr & 63;
        int b = rbase >> 10, l0 = rbase & 1023;
        if (region < 2) {
#pragma unroll
          for (int r = 0; r < 4; ++r) {
            int l = l0 + r;
            float val = acc[i][j][r] + bv;
            float partner = __shfl_xor(val, 1);
            float cc = cosb[l * 64 + d], sn = sinb[l * 64 + d];
            float out = (d & 1) ? (val * cc + partner * sn) : (val * cc - partner * sn);
            if (region == 0) out *= 0.125f;
            u16* dst = (region == 0) ? qo : ko;
            dst[((size_t)(b * 16 + hh) * 1024 + l) * 64 + d] = f2bf(out);
          }
        } else {
          union { ushort4 s4; u32 w[2]; } vv;
          vv.w[0] = cvtpk(acc[i][j][0] + bv, acc[i][j][1] + bv);
          vv.w[1] = cvtpk(acc[i][j][2] + bv, acc[i][j][3] + bv);
          *(ushort4*)(vto + (size_t)(b * 16 + hh) * 65536 + (size_t)d * 1024 + l0) = vv.s4;
        }
      } else {
#pragma unroll
        for (int r = 0; r < 4; ++r) {
          int row = rbase + r;
          float val = acc[i][j][r] + bv;
          if (EPI == 0) {
            Cb[(size_t)row * N + cg] = f2bf(val);
          } else {
            float tt = 0.7978845608028654f * (val + 0.044715f * val * val * val);
            float e = __expf(2.f * tt);
            float th = 1.f - 2.f / (e + 1.f);
            Cb[(size_t)row * N + cg] = f2bf(0.5f * val * (1.f + th));
          }
        }
      }
    }
  }
}

// ---------------- GEMM 128x128, BK=32, 4 waves, 3-slot ring, residual epilogue ----------------
__global__ __launch_bounds__(256) void gemm_res128_kernel(
    const u16* __restrict__ A, const u16* __restrict__ BT, const float* __restrict__ bias,
    const float* __restrict__ xin, float* __restrict__ xout, const float* __restrict__ mod,
    int g_off, int K) {
  __shared__ u16 lds[3][8192];  // slot: A [64 rows][128B] 4KB, then B 4KB
  const int tid = threadIdx.x;
  const int lane = tid & 63, wave = tid >> 6;
  const int lq = lane & 15, lk = lane >> 4;
  const int wr = wave >> 1, wc = wave & 1;  // wave tile 64 x 64
  const int m0 = blockIdx.x * 128, n0 = blockIdx.y * 128;

  f32x4 acc[4][4];
#pragma unroll
  for (int i = 0; i < 4; ++i)
#pragma unroll
    for (int j = 0; j < 4; ++j) acc[i][j] = (f32x4){0.f, 0.f, 0.f, 0.f};

  auto STAGE = [&](int slot, int t) {
    int kt = t * 32;
    char* Ab = (char*)lds[slot];
    char* Bb = (char*)(lds[slot] + 4096);
#pragma unroll
    for (int q = 0; q < 2; ++q) {
      int u = tid + q * 256;         // 512 chunks each for A and B
      int r = u >> 3, cpos = u & 7;
      int g = cpos ^ (r & 7);        // pre-swizzled source chunk
      gload16(A + (size_t)(m0 + 2 * r + (g >> 2)) * K + kt + (g & 3) * 8, Ab + u * 16);
      gload16(BT + (size_t)(n0 + 2 * r + (g >> 2)) * K + kt + (g & 3) * 8, Bb + u * 16);
    }
  };

  const int NT = K >> 5;
  STAGE(0, 0); STAGE(1, 1);
  int slot = 0;
  for (int t = 0; t < NT; ++t) {
    if (t + 1 < NT) asm volatile("s_waitcnt vmcnt(4)" ::: "memory");
    else asm volatile("s_waitcnt vmcnt(0)" ::: "memory");
    __builtin_amdgcn_s_barrier();
    __builtin_amdgcn_sched_barrier(0);
    if (t + 2 < NT) { int ns = slot + 2; if (ns >= 3) ns -= 3; STAGE(ns, t + 2); }
    const char* Ab = (const char*)lds[slot];
    const char* Bb = (const char*)(lds[slot] + 4096);
    bf16x8 af[4], bfr[4];
#pragma unroll
    for (int i = 0; i < 4; ++i) {
      int mrow = wr * 64 + i * 16 + lq;
      int r = mrow >> 1, g = (mrow & 1) * 4 + lk;
      af[i] = *(const bf16x8*)(Ab + r * 128 + ((g ^ (r & 7)) << 4));
    }
#pragma unroll
    for (int j = 0; j < 4; ++j) {
      int nrow = wc * 64 + j * 16 + lq;
      int r = nrow >> 1, g = (nrow & 1) * 4 + lk;
      bfr[j] = *(const bf16x8*)(Bb + r * 128 + ((g ^ (r & 7)) << 4));
    }
    __builtin_amdgcn_s_setprio(1);
#pragma unroll
    for (int i = 0; i < 4; ++i)
#pragma unroll
      for (int j = 0; j < 4; ++j) acc[i][j] = MFMA32(af[i], bfr[j], acc[i][j]);
    __builtin_amdgcn_s_setprio(0);
    ++slot; if (slot >= 3) slot = 0;
  }

#pragma unroll
  for (int i = 0; i < 4; ++i) {
    int rbase = m0 + wr * 64 + i * 16 + lk * 4;
#pragma unroll
    for (int j = 0; j < 4; ++j) {
      int cg = n0 + wc * 64 + j * 16 + lq;
      float bv = bias[cg];
#pragma unroll
      for (int r = 0; r < 4; ++r) {
        int row = rbase + r;
        float val = acc[i][j][r] + bv;
        int b = row >> 10;
        float g = mod[(size_t)b * 6144 + g_off + cg];
        float xv = xin[(size_t)row * 1024 + cg];
        xout[(size_t)row * 1024 + cg] = (xv + g * val) * SKIPF;
      }
    }
  }
}

// ---------------- flash attention: 1024 blocks (16 qt x 64 bh), 16 q-rows/wave, ----------------
// 2-slot LDS ring (32 KB -> 4 blocks/CU), wait->barrier->stage(t+1)->compute.
__global__ __launch_bounds__(256) void attn_kernel(const u16* __restrict__ qb,
                                                   const u16* __restrict__ kb,
                                                   const u16* __restrict__ vt,
                                                   u16* __restrict__ ob) {
  __shared__ u16 ktile[2][4096];
  __shared__ u16 vtile[2][4096];
  int nid = (blockIdx.x & 7) * 128 + (blockIdx.x >> 3);  // XCD chunk swizzle: 8 bh per XCD
  int qt = nid & 15, bh = nid >> 4;
  int tid = threadIdx.x;
  int lane = tid & 63, wave = tid >> 6;
  int lq = lane & 15, lk = lane >> 4;
  const u16* Q = qb + (size_t)bh * 65536;
  const u16* Kp = kb + (size_t)bh * 65536;
  const u16* VT = vt + (size_t)bh * 65536;
  int qbase = qt * 64 + wave * 16;

  bf16x8 qf0 = *(const bf16x8*)(Q + (size_t)(qbase + lq) * 64 + lk * 8);
  bf16x8 qf1 = *(const bf16x8*)(Q + (size_t)(qbase + lq) * 64 + 32 + lk * 8);

  auto stage_one = [&](int buf, int kvb, int u) {
    int r = u >> 3;
    int cc = ((u & 7) ^ (r & 7)) * 8;
    gload16(Kp + (size_t)(kvb + r) * 64 + cc, (char*)ktile[buf] + u * 16);
    gload16(VT + (size_t)r * 1024 + kvb + cc, (char*)vtile[buf] + u * 16);
  };

  float mrun = -1e30f, lsum = 0.f;
  f32x4 oacc[4];
#pragma unroll
  for (int f = 0; f < 4; ++f) oacc[f] = (f32x4){0.f, 0.f, 0.f, 0.f};
  const f32x4 z4 = (f32x4){0.f, 0.f, 0.f, 0.f};

  stage_one(0, 0, tid); stage_one(0, 0, tid + 256);
  int slot = 0;
  for (int t = 0; t < 16; ++t) {
    asm volatile("s_waitcnt vmcnt(0)" ::: "memory");
    __builtin_amdgcn_s_barrier();
    __builtin_amdgcn_sched_barrier(0);
    if (t + 1 < 16) {
      stage_one(slot ^ 1, (t + 1) * 64, tid);
      stage_one(slot ^ 1, (t + 1) * 64, tid + 256);
    }
    const char* kb_ = (const char*)ktile[slot];
    const char* vb_ = (const char*)vtile[slot];
    f32x4 st[4];
    __builtin_amdgcn_s_setprio(1);
#pragma unroll
    for (int s = 0; s < 4; ++s) {
      int r = s * 16 + lq;
      int sw = (r & 7) << 4;
      bf16x8 kf0 = *(const bf16x8*)(kb_ + r * 128 + ((lk * 16) ^ sw));
      bf16x8 kf1 = *(const bf16x8*)(kb_ + r * 128 + ((64 + lk * 16) ^ sw));
      st[s] = MFMA32(kf0, qf0, z4);
      st[s] = MFMA32(kf1, qf1, st[s]);
    }
    __builtin_amdgcn_s_setprio(0);
    float pm = -1e30f;
#pragma unroll
    for (int s = 0; s < 4; ++s)
#pragma unroll
      for (int r = 0; r < 4; ++r) pm = fmaxf(pm, st[s][r]);
    pm = fmaxf(pm, __shfl_xor(pm, 16));
    pm = fmaxf(pm, __shfl_xor(pm, 32));
    if (!__all(pm - mrun <= 8.f)) {
      float mnew = fmaxf(mrun, pm);
      float corr = __expf(mrun - mnew);
      float c0 = __shfl(corr, lk * 4 + 0), c1 = __shfl(corr, lk * 4 + 1);
      float c2 = __shfl(corr, lk * 4 + 2), c3 = __shfl(corr, lk * 4 + 3);
#pragma unroll
      for (int f = 0; f < 4; ++f) {
        oacc[f][0] *= c0; oacc[f][1] *= c1;
        oacc[f][2] *= c2; oacc[f][3] *= c3;
      }
      lsum *= corr;
      mrun = mnew;
    }
    bf16x4 pf[4];
    float ps = 0.f;
#pragma unroll
    for (int s = 0; s < 4; ++s) {
      float p0 = __expf(st[s][0] - mrun);
      float p1 = __expf(st[s][1] - mrun);
      float p2 = __expf(st[s][2] - mrun);
      float p3 = __expf(st[s][3] - mrun);
      ps += p0 + p1 + p2 + p3;
      union { bf16x4 v; u32 w[2]; } pu;
      pu.w[0] = cvtpk(p0, p1);
      pu.w[1] = cvtpk(p2, p3);
      pf[s] = pu.v;
    }
    ps += __shfl_xor(ps, 16);
    ps += __shfl_xor(ps, 32);
    lsum += ps;
    __builtin_amdgcn_s_setprio(1);
#pragma unroll
    for (int f = 0; f < 4; ++f) {
      int r = lq + f * 16;
      int sw = (r & 7) << 4;
#pragma unroll
      for (int s = 0; s < 4; ++s) {
        bf16x4 vf = *(const bf16x4*)(vb_ + r * 128 + ((s * 32 + lk * 8) ^ sw));
        oacc[f] = MFMA16(pf[s], vf, oacc[f]);
      }
    }
    __builtin_amdgcn_s_setprio(0);
    slot ^= 1;
  }

  int b = bh >> 4, hh = bh & 15;
  float inv = 1.f / lsum;
  float i0 = __shfl(inv, lk * 4 + 0), i1 = __shfl(inv, lk * 4 + 1);
  float i2 = __shfl(inv, lk * 4 + 2), i3 = __shfl(inv, lk * 4 + 3);
#pragma unroll
  for (int f = 0; f < 4; ++f) {
#pragma unroll
    for (int j = 0; j < 4; ++j) {
      int qrow = qbase + lk * 4 + j;
      float sc = (j == 0) ? i0 : (j == 1) ? i1 : (j == 2) ? i2 : i3;
      ob[((size_t)(b * 1024 + qrow)) * 1024 + hh * 64 + lq + f * 16] = f2bf(oacc[f][j] * sc);
    }
  }
}

// ---------------- launch ----------------

extern "C" void kernel_launch(void* const* d_in, const int* in_sizes, int n_in,
                              void* d_out, int out_size, void* d_ws, size_t ws_size,
                              hipStream_t stream) {
  const float* x = (const float*)d_in[0];
  const float* c = (const float*)d_in[1];
  const float* t = (const float*)d_in[2];
  const float* cosb = (const float*)d_in[4];
  const float* sinb = (const float*)d_in[5];
  const float* qkv_w = (const float*)d_in[6];
  const float* qkv_b = (const float*)d_in[7];
  const float* proj_w = (const float*)d_in[8];
  const float* proj_b = (const float*)d_in[9];
  const float* w1 = (const float*)d_in[10];
  const float* b1 = (const float*)d_in[11];
  const float* w2 = (const float*)d_in[12];
  const float* b2 = (const float*)d_in[13];
  const float* aw = (const float*)d_in[14];
  const float* ab = (const float*)d_in[15];

  constexpr size_t OFF_X = 0;                          // 16 MB f32 residual
  constexpr size_t OFF_H = OFF_X + 16777216;           // 8 MB bf16 h
  constexpr size_t OFF_BIG = OFF_H + 8388608;          // 32 MB bf16 m1
  constexpr size_t OFF_Q = OFF_BIG + 33554432;         // 8 MB
  constexpr size_t OFF_K = OFF_Q + 8388608;
  constexpr size_t OFF_V = OFF_K + 8388608;            // vt [bh][d][l]
  constexpr size_t OFF_AO = OFF_V + 8388608;
  constexpr size_t OFF_WQ = OFF_AO + 8388608;          // 6 MB bf16 qkv_w^T
  constexpr size_t OFF_WP = OFF_WQ + 6291456;          // 2 MB
  constexpr size_t OFF_W1 = OFF_WP + 2097152;          // 8 MB
  constexpr size_t OFF_W2 = OFF_W1 + 8388608;          // 8 MB
  constexpr size_t OFF_MOD = OFF_W2 + 8388608;         // mod 96 KB
  constexpr size_t OFF_PART = OFF_MOD + 98304;         // partials 3 MB

  char* ws = (char*)d_ws;
  float* x_cur = (float*)(ws + OFF_X);
  u16* h = (u16*)(ws + OFF_H);
  u16* big = (u16*)(ws + OFF_BIG);
  u16* qv = (u16*)(ws + OFF_Q);
  u16* kv = (u16*)(ws + OFF_K);
  u16* vt = (u16*)(ws + OFF_V);
  u16* ao = (u16*)(ws + OFF_AO);
  u16* wTq = (u16*)(ws + OFF_WQ);
  u16* wTp = (u16*)(ws + OFF_WP);
  u16* wT1 = (u16*)(ws + OFF_W1);
  u16* wT2 = (u16*)(ws + OFF_W2);
  float* mod = (float*)(ws + OFF_MOD);
  float* part = (float*)(ws + OFF_PART);

  for (int L = 0; L < 8; ++L) {
    const float* awL = aw + (size_t)L * 1024 * 6144;
    const float* abL = ab + (size_t)L * 6144;
    const float* qwL = qkv_w + (size_t)L * 1024 * 3072;
    const float* qbL = qkv_b + (size_t)L * 3072;
    const float* pwL = proj_w + (size_t)L * 1024 * 1024;
    const float* pbL = proj_b + (size_t)L * 1024;
    const float* w1L = w1 + (size_t)L * 1024 * 4096;
    const float* b1L = b1 + (size_t)L * 4096;
    const float* w2L = w2 + (size_t)L * 4096 * 1024;
    const float* b2L = b2 + (size_t)L * 1024;

    const float* xin = (L == 0) ? x : x_cur;
    float* xout2 = (L == 7) ? (float*)d_out : x_cur;

    adaln_part_kernel<<<dim3(24, 32), 256, 0, stream>>>(c, t, awL, part);
    adaln_reduce_kernel<<<96, 256, 0, stream>>>(part, abL, mod);
    wtrans4_kernel<<<12288, dim3(32, 8), 0, stream>>>(qwL, wTq, pwL, wTp, w1L, wT1, w2L, wT2);

    ln_mod_kernel<<<4096, 256, 0, stream>>>(xin, mod, h, 0, 1024);
    gemm256r_kernel<2><<<192, 512, 0, stream>>>(h, wTq, qbL, nullptr, 12, 3072, 1024,
                                                cosb, sinb, qv, kv, vt);
    attn_kernel<<<1024, 256, 0, stream>>>(qv, kv, vt, ao);
    gemm_res128_kernel<<<dim3(32, 8), 256, 0, stream>>>(ao, wTp, pbL, xin, x_cur, mod, 2048, 1024);
    ln_mod_kernel<<<4096, 256, 0, stream>>>(x_cur, mod, h, 3072, 4096);
    gemm256r_kernel<1><<<256, 512, 0, stream>>>(h, wT1, b1L, big, 16, 4096, 1024,
                                                nullptr, nullptr, nullptr, nullptr, nullptr);
    gemm_res128_kernel<<<dim3(32, 8), 256, 0, stream>>>(big, wT2, b2L, x_cur, xout2, mod, 5120, 4096);
  }
}